// Round 1
// baseline (241.208 us; speedup 1.0000x reference)
//
#include <hip/hip_runtime.h>

#define HH 8
#define LL 4
#define PP 2
#define DD 32
#define CC 256
#define NVV 21760
#define NQQ 1000
#define BB 4

// ---------------------------------------------------------------------------
// Kernel 1: v[b,h,n,d] = sum_c value[b,n,c] * W_val[c, h*32+d] + b_val
// Classic fp32 tiled GEMM: BM=64, BN=64, BK=16, 256 threads, 4x4 per thread.
// M = B*NV = 87040 (NV % 64 == 0 so a 64-row tile never crosses a batch).
// ---------------------------------------------------------------------------
__global__ __launch_bounds__(256) void valproj_kernel(
    const float* __restrict__ value, const float* __restrict__ Wv,
    const float* __restrict__ bv, float* __restrict__ v_out)
{
    __shared__ float As[16][64];  // [k][m]
    __shared__ float Bs[16][64];  // [k][n]
    const int tid = threadIdx.x;
    const int tx = tid & 15, ty = tid >> 4;
    const int bm = blockIdx.y * 64;
    const int bn = blockIdx.x * 64;
    float acc[4][4] = {};

    const int ar = tid >> 2;          // A row within tile (0..63)
    const int ak = (tid & 3) * 4;     // A k offset (0,4,8,12)
    const int brow = tid >> 4;        // B k row (0..15)
    const int bcol = (tid & 15) * 4;  // B col (0..60)

    for (int k0 = 0; k0 < CC; k0 += 16) {
        float4 av = *reinterpret_cast<const float4*>(
            &value[(size_t)(bm + ar) * CC + k0 + ak]);
        float4 bw = *reinterpret_cast<const float4*>(
            &Wv[(size_t)(k0 + brow) * CC + bn + bcol]);
        __syncthreads();
        As[ak + 0][ar] = av.x;
        As[ak + 1][ar] = av.y;
        As[ak + 2][ar] = av.z;
        As[ak + 3][ar] = av.w;
        *reinterpret_cast<float4*>(&Bs[brow][bcol]) = bw;
        __syncthreads();
#pragma unroll
        for (int kk = 0; kk < 16; ++kk) {
            float a[4], bb[4];
#pragma unroll
            for (int i = 0; i < 4; ++i) a[i] = As[kk][ty * 4 + i];
#pragma unroll
            for (int j = 0; j < 4; ++j) bb[j] = Bs[kk][tx * 4 + j];
#pragma unroll
            for (int i = 0; i < 4; ++i)
#pragma unroll
                for (int j = 0; j < 4; ++j) acc[i][j] += a[i] * bb[j];
        }
    }

    const int col0 = bn + tx * 4;
    const int h = col0 >> 5;
    const int d0 = col0 & 31;
    const int b = bm / NVV;  // whole tile within one batch
#pragma unroll
    for (int i = 0; i < 4; ++i) {
        int m = bm + ty * 4 + i;
        int n = m - b * NVV;
        float4 o;
        o.x = acc[i][0] + bv[col0 + 0];
        o.y = acc[i][1] + bv[col0 + 1];
        o.z = acc[i][2] + bv[col0 + 2];
        o.w = acc[i][3] + bv[col0 + 3];
        *reinterpret_cast<float4*>(
            &v_out[(size_t)((b * HH + h) * NVV + n) * DD + d0]) = o;
    }
}

// ---------------------------------------------------------------------------
// Kernel 2: fused per-query. One block per (b,q), 256 threads.
// Phase 1: offsets (128 dots) + attn logits (64 dots) from LDS-staged query.
// Phase 2: 8-thread softmax over L*P=8 per head.
// Phase 3: thread (h=tid/32, d=tid%32) gathers 8 samples x 4 corners.
// Phase 4: out row = mid @ W_out + b_out (one 256-dot per thread).
// ---------------------------------------------------------------------------
__global__ __launch_bounds__(256) void msda_fused_kernel(
    const float* __restrict__ query, const float* __restrict__ refp,
    const float* __restrict__ W_off, const float* __restrict__ b_off,
    const float* __restrict__ W_attn, const float* __restrict__ b_attn,
    const float* __restrict__ W_out, const float* __restrict__ b_out,
    const float* __restrict__ v,  // [B,H,NV,D]
    float* __restrict__ out)
{
    __shared__ float q_lds[CC];
    __shared__ float off_lds[128];
    __shared__ float attn_lds[64];
    __shared__ float ref_lds[8];
    __shared__ float mid_lds[CC];

    const int tid = threadIdx.x;
    const int bq = blockIdx.x;  // b*NQ + q
    const int b = bq / NQQ;

    q_lds[tid] = query[(size_t)bq * CC + tid];
    if (tid < 8) ref_lds[tid] = refp[(size_t)bq * 8 + tid];
    __syncthreads();

    if (tid < 128) {
        float s = b_off[tid];
        for (int c = 0; c < CC; ++c) s += q_lds[c] * W_off[c * 128 + tid];
        off_lds[tid] = s;
    } else if (tid < 192) {
        int j = tid - 128;
        float s = b_attn[j];
        for (int c = 0; c < CC; ++c) s += q_lds[c] * W_attn[c * 64 + j];
        attn_lds[j] = s;
    }
    __syncthreads();

    if (tid < 8) {
        int h = tid;
        float m = -1e30f;
        for (int j = 0; j < 8; ++j) m = fmaxf(m, attn_lds[h * 8 + j]);
        float s = 0.f, e[8];
        for (int j = 0; j < 8; ++j) {
            e[j] = expf(attn_lds[h * 8 + j] - m);
            s += e[j];
        }
        float inv = 1.f / s;
        for (int j = 0; j < 8; ++j) attn_lds[h * 8 + j] = e[j] * inv;
    }
    __syncthreads();

    const int h = tid >> 5, d = tid & 31;
    const float* vh = v + (size_t)(b * HH + h) * NVV * DD;
    const int starts[4] = {0, 16384, 20480, 21504};
    const float szs[4] = {128.f, 64.f, 32.f, 16.f};
    float acc = 0.f;
#pragma unroll
    for (int l = 0; l < LL; ++l) {
        const float S = szs[l];
        const int Wl = (int)S;
        const float refx = ref_lds[l * 2 + 0];
        const float refy = ref_lds[l * 2 + 1];
        const float* vl = vh + (size_t)starts[l] * DD;
#pragma unroll
        for (int p = 0; p < PP; ++p) {
            const int oi = h * 16 + l * 4 + p * 2;
            float lx = refx + off_lds[oi + 0] / S;
            float ly = refy + off_lds[oi + 1] / S;
            float x = lx * S - 0.5f;
            float y = ly * S - 0.5f;
            float x0f = floorf(x), y0f = floorf(y);
            float fx = x - x0f, fy = y - y0f;
            int x0 = (int)x0f, y0 = (int)y0f;
            float a = attn_lds[h * 8 + l * 2 + p];
            float sacc = 0.f;
#pragma unroll
            for (int dy = 0; dy < 2; ++dy) {
#pragma unroll
                for (int dx = 0; dx < 2; ++dx) {
                    int xi = x0 + dx, yi = y0 + dy;
                    float w = (dx ? fx : 1.f - fx) * (dy ? fy : 1.f - fy);
                    bool valid = (xi >= 0) && (xi < Wl) && (yi >= 0) && (yi < Wl);
                    int xc = min(max(xi, 0), Wl - 1);
                    int yc = min(max(yi, 0), Wl - 1);
                    float g = vl[(size_t)(yc * Wl + xc) * DD + d];
                    sacc += g * (valid ? w : 0.f);
                }
            }
            acc += a * sacc;
        }
    }
    mid_lds[tid] = acc;
    __syncthreads();

    float o = b_out[tid];
    for (int c = 0; c < CC; ++c) o += mid_lds[c] * W_out[c * CC + tid];
    out[(size_t)bq * CC + tid] = o;
}

extern "C" void kernel_launch(void* const* d_in, const int* in_sizes, int n_in,
                              void* d_out, int out_size, void* d_ws, size_t ws_size,
                              hipStream_t stream) {
    const float* query  = (const float*)d_in[0];
    const float* value  = (const float*)d_in[1];
    const float* refp   = (const float*)d_in[2];
    const float* W_off  = (const float*)d_in[3];
    const float* b_off  = (const float*)d_in[4];
    const float* W_attn = (const float*)d_in[5];
    const float* b_attn = (const float*)d_in[6];
    const float* W_val  = (const float*)d_in[7];
    const float* b_val  = (const float*)d_in[8];
    const float* W_out  = (const float*)d_in[9];
    const float* b_out  = (const float*)d_in[10];
    float* out = (float*)d_out;
    float* v_ws = (float*)d_ws;  // B*H*NV*D floats = 89.1 MB

    dim3 g1(CC / 64, (BB * NVV) / 64);  // (4, 1360)
    valproj_kernel<<<g1, 256, 0, stream>>>(value, W_val, b_val, v_ws);
    msda_fused_kernel<<<BB * NQQ, 256, 0, stream>>>(
        query, refp, W_off, b_off, W_attn, b_attn, W_out, b_out, v_ws, out);
}

// Round 2
// 101.617 us; speedup vs baseline: 2.3737x; 2.3737x over previous
//
#include <hip/hip_runtime.h>

#define HH 8
#define LL 4
#define PP 2
#define DD 32
#define CC 256
#define NVV 21760
#define NQQ 1000
#define BB 4
#define QB 8

typedef __attribute__((ext_vector_type(8))) short short8;
typedef __attribute__((ext_vector_type(4))) float f32x4;

__device__ __forceinline__ unsigned short f2bf(float f) {
    unsigned u = __float_as_uint(f);
    u += 0x7FFF + ((u >> 16) & 1);  // round-to-nearest-even
    return (unsigned short)(u >> 16);
}
__device__ __forceinline__ float bf2f(unsigned short h) {
    return __uint_as_float(((unsigned)h) << 16);
}

// ---------------------------------------------------------------------------
// Kernel 0: WT[n][c] = bf16(W_val[c][n])  (transpose + convert, 64K elems)
// ---------------------------------------------------------------------------
__global__ void prep_kernel(const float* __restrict__ Wv,
                            unsigned short* __restrict__ WT) {
    int c = blockIdx.x, n = threadIdx.x;
    WT[n * CC + c] = f2bf(Wv[c * CC + n]);
}

// ---------------------------------------------------------------------------
// Kernel 1: v[b,h,n,d] (bf16) = value[b,n,:] @ W_val[:, h*32+d] + b_val
// MFMA 16x16x32 bf16. BM=64, BN=256 (full N -> value read exactly once),
// BK=32. 4 waves, each owns 64x64 (4x4 fragments). LDS rows padded to 40
// shorts (80 B, 16B-aligned) to break bank-conflict stride.
// ---------------------------------------------------------------------------
__global__ __launch_bounds__(256) void valproj_mfma(
    const float* __restrict__ value, const unsigned short* __restrict__ WT,
    const float* __restrict__ bv, unsigned short* __restrict__ v_out)
{
    __shared__ unsigned short As[64][40];   // [m][k] padded
    __shared__ unsigned short Bs[256][40];  // [n][k] padded
    const int tid = threadIdx.x;
    const int lane = tid & 63;
    const int wave = tid >> 6;
    const int bm = blockIdx.x * 64;
    const int b = bm / NVV;  // NVV % 64 == 0 -> tile within one batch

    f32x4 acc[4][4] = {};

    const int ar = tid >> 2;         // A row 0..63
    const int ak = (tid & 3) * 8;    // A k offset 0,8,16,24
    const int lr = lane & 15;
    const int lk = (lane >> 4) * 8;

    for (int k0 = 0; k0 < CC; k0 += 32) {
        // issue global loads early
        const float* asrc = &value[(size_t)(bm + ar) * CC + k0 + ak];
        float4 f0 = *(const float4*)(asrc);
        float4 f1 = *(const float4*)(asrc + 4);
        const unsigned short* bsrc = &WT[(size_t)tid * CC + k0];
        short8 w0 = *(const short8*)(bsrc);
        short8 w1 = *(const short8*)(bsrc + 8);
        short8 w2 = *(const short8*)(bsrc + 16);
        short8 w3 = *(const short8*)(bsrc + 24);

        __syncthreads();  // prior iteration's LDS reads done
        short8 av;
        av[0] = (short)f2bf(f0.x); av[1] = (short)f2bf(f0.y);
        av[2] = (short)f2bf(f0.z); av[3] = (short)f2bf(f0.w);
        av[4] = (short)f2bf(f1.x); av[5] = (short)f2bf(f1.y);
        av[6] = (short)f2bf(f1.z); av[7] = (short)f2bf(f1.w);
        *(short8*)&As[ar][ak] = av;
        *(short8*)&Bs[tid][0]  = w0;
        *(short8*)&Bs[tid][8]  = w1;
        *(short8*)&Bs[tid][16] = w2;
        *(short8*)&Bs[tid][24] = w3;
        __syncthreads();

        short8 afr[4], bfr[4];
#pragma unroll
        for (int mf = 0; mf < 4; ++mf)
            afr[mf] = *(const short8*)&As[mf * 16 + lr][lk];
#pragma unroll
        for (int nf = 0; nf < 4; ++nf)
            bfr[nf] = *(const short8*)&Bs[wave * 64 + nf * 16 + lr][lk];
#pragma unroll
        for (int mf = 0; mf < 4; ++mf)
#pragma unroll
            for (int nf = 0; nf < 4; ++nf)
                acc[mf][nf] = __builtin_amdgcn_mfma_f32_16x16x32_bf16(
                    afr[mf], bfr[nf], acc[mf][nf], 0, 0, 0);
    }

    // epilogue: D lane mapping col=lane&15, row=(lane>>4)*4+r (m89-verified)
#pragma unroll
    for (int nf = 0; nf < 4; ++nf) {
        int col = wave * 64 + nf * 16 + lr;
        int h = col >> 5, d = col & 31;
        float bias = bv[col];
#pragma unroll
        for (int mf = 0; mf < 4; ++mf) {
#pragma unroll
            for (int r = 0; r < 4; ++r) {
                int m = bm + mf * 16 + (lane >> 4) * 4 + r;
                int n = m - b * NVV;
                v_out[(size_t)((b * HH + h) * NVV + n) * DD + d] =
                    f2bf(acc[mf][nf][r] + bias);
            }
        }
    }
}

// ---------------------------------------------------------------------------
// Kernel 2: fused per-query work, QB=8 queries per block (weight traffic /8).
// Phase 1: offsets+logits via outer-product dots (W column read once, 8 FMA).
// Phase 2: softmax (64 threads = 8q x 8h).
// Phase 3: bilinear gather from bf16 v, 8 queries per (h,d) thread.
// Phase 4: out = mid @ W_out + b_out, 8 accumulators per column.
// ---------------------------------------------------------------------------
__global__ __launch_bounds__(256) void msda_fused2(
    const float* __restrict__ query, const float* __restrict__ refp,
    const float* __restrict__ W_off, const float* __restrict__ b_off,
    const float* __restrict__ W_attn, const float* __restrict__ b_attn,
    const float* __restrict__ W_out, const float* __restrict__ b_out,
    const unsigned short* __restrict__ v,  // [B,H,NV,D] bf16
    float* __restrict__ out)
{
    __shared__ float qT[CC][QB];     // transposed queries
    __shared__ float refl[QB][8];
    __shared__ float offl[QB][128];
    __shared__ float attnl[QB][64];
    __shared__ float midT[CC][QB];   // transposed mid

    const int tid = threadIdx.x;
    const int bq0 = blockIdx.x * QB;       // NQQ % QB == 0
    const int b = bq0 / NQQ;

#pragma unroll
    for (int qi = 0; qi < QB; ++qi)
        qT[tid][qi] = query[(size_t)(bq0 + qi) * CC + tid];
    if (tid < QB * 8) refl[tid >> 3][tid & 7] = refp[(size_t)bq0 * 8 + tid];
    __syncthreads();

    if (tid < 128) {
        float acc[QB];
        float bias = b_off[tid];
#pragma unroll
        for (int qi = 0; qi < QB; ++qi) acc[qi] = bias;
#pragma unroll 4
        for (int c = 0; c < CC; ++c) {
            float w = W_off[c * 128 + tid];
            f32x4 qa = *(const f32x4*)&qT[c][0];
            f32x4 qb = *(const f32x4*)&qT[c][4];
            acc[0] += qa[0] * w; acc[1] += qa[1] * w;
            acc[2] += qa[2] * w; acc[3] += qa[3] * w;
            acc[4] += qb[0] * w; acc[5] += qb[1] * w;
            acc[6] += qb[2] * w; acc[7] += qb[3] * w;
        }
#pragma unroll
        for (int qi = 0; qi < QB; ++qi) offl[qi][tid] = acc[qi];
    } else if (tid < 192) {
        int j = tid - 128;
        float acc[QB];
        float bias = b_attn[j];
#pragma unroll
        for (int qi = 0; qi < QB; ++qi) acc[qi] = bias;
#pragma unroll 4
        for (int c = 0; c < CC; ++c) {
            float w = W_attn[c * 64 + j];
            f32x4 qa = *(const f32x4*)&qT[c][0];
            f32x4 qb = *(const f32x4*)&qT[c][4];
            acc[0] += qa[0] * w; acc[1] += qa[1] * w;
            acc[2] += qa[2] * w; acc[3] += qa[3] * w;
            acc[4] += qb[0] * w; acc[5] += qb[1] * w;
            acc[6] += qb[2] * w; acc[7] += qb[3] * w;
        }
#pragma unroll
        for (int qi = 0; qi < QB; ++qi) attnl[qi][j] = acc[qi];
    }
    __syncthreads();

    if (tid < QB * HH) {
        int qi = tid >> 3, h = tid & 7;
        float m = -1e30f;
#pragma unroll
        for (int j = 0; j < 8; ++j) m = fmaxf(m, attnl[qi][h * 8 + j]);
        float s = 0.f, e[8];
#pragma unroll
        for (int j = 0; j < 8; ++j) {
            e[j] = __expf(attnl[qi][h * 8 + j] - m);
            s += e[j];
        }
        float inv = 1.f / s;
#pragma unroll
        for (int j = 0; j < 8; ++j) attnl[qi][h * 8 + j] = e[j] * inv;
    }
    __syncthreads();

    const int h = tid >> 5, d = tid & 31;
    const unsigned short* vh = v + (size_t)(b * HH + h) * NVV * DD;
    const int starts[4] = {0, 16384, 20480, 21504};
    const float szs[4] = {128.f, 64.f, 32.f, 16.f};

#pragma unroll
    for (int qi = 0; qi < QB; ++qi) {
        float acc = 0.f;
#pragma unroll
        for (int l = 0; l < LL; ++l) {
            const float S = szs[l];
            const int Wl = (int)S;
            const float refx = refl[qi][l * 2 + 0];
            const float refy = refl[qi][l * 2 + 1];
            const unsigned short* vl = vh + (size_t)starts[l] * DD;
#pragma unroll
            for (int p = 0; p < PP; ++p) {
                const int oi = h * 16 + l * 4 + p * 2;
                float lx = refx + offl[qi][oi + 0] / S;
                float ly = refy + offl[qi][oi + 1] / S;
                float x = lx * S - 0.5f;
                float y = ly * S - 0.5f;
                float x0f = floorf(x), y0f = floorf(y);
                float fx = x - x0f, fy = y - y0f;
                int x0 = (int)x0f, y0 = (int)y0f;
                float a = attnl[qi][h * 8 + l * 2 + p];
                float sacc = 0.f;
#pragma unroll
                for (int dy = 0; dy < 2; ++dy) {
#pragma unroll
                    for (int dx = 0; dx < 2; ++dx) {
                        int xi = x0 + dx, yi = y0 + dy;
                        float w = (dx ? fx : 1.f - fx) * (dy ? fy : 1.f - fy);
                        bool valid = (xi >= 0) && (xi < Wl) && (yi >= 0) && (yi < Wl);
                        int xc = min(max(xi, 0), Wl - 1);
                        int yc = min(max(yi, 0), Wl - 1);
                        float g = bf2f(vl[(size_t)(yc * Wl + xc) * DD + d]);
                        sacc += g * (valid ? w : 0.f);
                    }
                }
                acc += a * sacc;
            }
        }
        midT[h * 32 + d][qi] = acc;
    }
    __syncthreads();

    float acc2[QB];
    float bias = b_out[tid];
#pragma unroll
    for (int qi = 0; qi < QB; ++qi) acc2[qi] = bias;
#pragma unroll 4
    for (int c = 0; c < CC; ++c) {
        float w = W_out[c * CC + tid];
        f32x4 ma = *(const f32x4*)&midT[c][0];
        f32x4 mb = *(const f32x4*)&midT[c][4];
        acc2[0] += ma[0] * w; acc2[1] += ma[1] * w;
        acc2[2] += ma[2] * w; acc2[3] += ma[3] * w;
        acc2[4] += mb[0] * w; acc2[5] += mb[1] * w;
        acc2[6] += mb[2] * w; acc2[7] += mb[3] * w;
    }
#pragma unroll
    for (int qi = 0; qi < QB; ++qi)
        out[(size_t)(bq0 + qi) * CC + tid] = acc2[qi];
}

extern "C" void kernel_launch(void* const* d_in, const int* in_sizes, int n_in,
                              void* d_out, int out_size, void* d_ws, size_t ws_size,
                              hipStream_t stream) {
    const float* query  = (const float*)d_in[0];
    const float* value  = (const float*)d_in[1];
    const float* refp   = (const float*)d_in[2];
    const float* W_off  = (const float*)d_in[3];
    const float* b_off  = (const float*)d_in[4];
    const float* W_attn = (const float*)d_in[5];
    const float* b_attn = (const float*)d_in[6];
    const float* W_val  = (const float*)d_in[7];
    const float* b_val  = (const float*)d_in[8];
    const float* W_out  = (const float*)d_in[9];
    const float* b_out  = (const float*)d_in[10];
    float* out = (float*)d_out;

    unsigned short* WT   = (unsigned short*)d_ws;                 // 128 KB
    unsigned short* v_ws = (unsigned short*)((char*)d_ws + 131072);  // 44.56 MB

    prep_kernel<<<CC, CC, 0, stream>>>(W_val, WT);
    valproj_mfma<<<(BB * NVV) / 64, 256, 0, stream>>>(value, WT, b_val, v_ws);
    msda_fused2<<<(BB * NQQ) / QB, 256, 0, stream>>>(
        query, refp, W_off, b_off, W_attn, b_attn, W_out, b_out, v_ws, out);
}

// Round 3
// 77.790 us; speedup vs baseline: 3.1008x; 1.3063x over previous
//
#include <hip/hip_runtime.h>

#define HH 8
#define LL 4
#define PP 2
#define DD 32
#define CC 256
#define NVV 21760
#define NQQ 1000
#define BB 4
#define NQT (BB * NQQ)   // 4000 total queries

typedef __attribute__((ext_vector_type(8))) short short8;
typedef __attribute__((ext_vector_type(4))) float f32x4;

__device__ __forceinline__ unsigned short f2bf(float f) {
    unsigned u = __float_as_uint(f);
    u += 0x7FFF + ((u >> 16) & 1);  // round-to-nearest-even
    return (unsigned short)(u >> 16);
}
__device__ __forceinline__ float bf2f(unsigned short h) {
    return __uint_as_float(((unsigned)h) << 16);
}

// ---------------------------------------------------------------------------
// Kernel 0: transpose+convert all weights to bf16 [n][k] layouts.
// blocks 0..255: WT_val; 256..447: W1T (=[W_off|W_attn]); 448..703: WoT.
// ---------------------------------------------------------------------------
__global__ void prep_kernel(const float* __restrict__ Wv,
                            const float* __restrict__ Woff,
                            const float* __restrict__ Wattn,
                            const float* __restrict__ Wout,
                            unsigned short* __restrict__ WT_val,
                            unsigned short* __restrict__ W1T,
                            unsigned short* __restrict__ WoT) {
    int blk = blockIdx.x, c = threadIdx.x;
    if (blk < 256) {
        WT_val[blk * CC + c] = f2bf(Wv[c * CC + blk]);
    } else if (blk < 448) {
        int n = blk - 256;
        float x = (n < 128) ? Woff[c * 128 + n] : Wattn[c * 64 + (n - 128)];
        W1T[n * CC + c] = f2bf(x);
    } else {
        int n = blk - 448;
        WoT[n * CC + c] = f2bf(Wout[c * CC + n]);
    }
}

// ---------------------------------------------------------------------------
// Kernel 1: v[b,h,n,d] (bf16) = value @ W_val + b_val. MFMA, BM=64, BN=256.
// (unchanged from round 2 — already at HBM floor)
// ---------------------------------------------------------------------------
__global__ __launch_bounds__(256) void valproj_mfma(
    const float* __restrict__ value, const unsigned short* __restrict__ WT,
    const float* __restrict__ bv, unsigned short* __restrict__ v_out)
{
    __shared__ unsigned short As[64][40];
    __shared__ unsigned short Bs[256][40];
    const int tid = threadIdx.x;
    const int lane = tid & 63;
    const int wave = tid >> 6;
    const int bm = blockIdx.x * 64;
    const int b = bm / NVV;

    f32x4 acc[4][4] = {};
    const int ar = tid >> 2;
    const int ak = (tid & 3) * 8;
    const int lr = lane & 15;
    const int lk = (lane >> 4) * 8;

    for (int k0 = 0; k0 < CC; k0 += 32) {
        const float* asrc = &value[(size_t)(bm + ar) * CC + k0 + ak];
        float4 f0 = *(const float4*)(asrc);
        float4 f1 = *(const float4*)(asrc + 4);
        const unsigned short* bsrc = &WT[(size_t)tid * CC + k0];
        short8 w0 = *(const short8*)(bsrc);
        short8 w1 = *(const short8*)(bsrc + 8);
        short8 w2 = *(const short8*)(bsrc + 16);
        short8 w3 = *(const short8*)(bsrc + 24);

        __syncthreads();
        short8 av;
        av[0] = (short)f2bf(f0.x); av[1] = (short)f2bf(f0.y);
        av[2] = (short)f2bf(f0.z); av[3] = (short)f2bf(f0.w);
        av[4] = (short)f2bf(f1.x); av[5] = (short)f2bf(f1.y);
        av[6] = (short)f2bf(f1.z); av[7] = (short)f2bf(f1.w);
        *(short8*)&As[ar][ak] = av;
        *(short8*)&Bs[tid][0]  = w0;
        *(short8*)&Bs[tid][8]  = w1;
        *(short8*)&Bs[tid][16] = w2;
        *(short8*)&Bs[tid][24] = w3;
        __syncthreads();

        short8 afr[4], bfr[4];
#pragma unroll
        for (int mf = 0; mf < 4; ++mf)
            afr[mf] = *(const short8*)&As[mf * 16 + lr][lk];
#pragma unroll
        for (int nf = 0; nf < 4; ++nf)
            bfr[nf] = *(const short8*)&Bs[wave * 64 + nf * 16 + lr][lk];
#pragma unroll
        for (int mf = 0; mf < 4; ++mf)
#pragma unroll
            for (int nf = 0; nf < 4; ++nf)
                acc[mf][nf] = __builtin_amdgcn_mfma_f32_16x16x32_bf16(
                    afr[mf], bfr[nf], acc[mf][nf], 0, 0, 0);
    }

#pragma unroll
    for (int nf = 0; nf < 4; ++nf) {
        int col = wave * 64 + nf * 16 + lr;
        int h = col >> 5, d = col & 31;
        float bias = bv[col];
#pragma unroll
        for (int mf = 0; mf < 4; ++mf) {
#pragma unroll
            for (int r = 0; r < 4; ++r) {
                int m = bm + mf * 16 + (lane >> 4) * 4 + r;
                int n = m - b * NVV;
                v_out[(size_t)((b * HH + h) * NVV + n) * DD + d] =
                    f2bf(acc[mf][nf][r] + bias);
            }
        }
    }
}

// ---------------------------------------------------------------------------
// Kernel 2: logits[4000,192] = query @ [W_off|W_attn] + bias. MFMA, BM=32.
// Grid 125 blocks. Wave w owns cols [48w, 48w+48), 2 row-frags x 3 col-frags.
// ---------------------------------------------------------------------------
__global__ __launch_bounds__(256) void logits_mfma(
    const float* __restrict__ query, const unsigned short* __restrict__ W1T,
    const float* __restrict__ b_off, const float* __restrict__ b_attn,
    float* __restrict__ logits)
{
    __shared__ unsigned short As[32][40];
    __shared__ unsigned short Bs[192][40];
    const int tid = threadIdx.x;
    const int lane = tid & 63;
    const int wave = tid >> 6;
    const int bm = blockIdx.x * 32;   // 125*32 = 4000 exact
    f32x4 acc[2][3] = {};
    const int lr = lane & 15;
    const int lk = (lane >> 4) * 8;

    for (int k0 = 0; k0 < CC; k0 += 32) {
        float4 f0 = {0, 0, 0, 0}, f1 = {0, 0, 0, 0};
        if (tid < 128) {
            const float* asrc =
                &query[(size_t)(bm + (tid >> 2)) * CC + k0 + (tid & 3) * 8];
            f0 = *(const float4*)(asrc);
            f1 = *(const float4*)(asrc + 4);
        }
        short8 w[3];
#pragma unroll
        for (int i = 0; i < 3; ++i) {
            int idx = i * 256 + tid;
            w[i] = *(const short8*)&W1T[(size_t)(idx >> 2) * CC + k0 + (idx & 3) * 8];
        }
        __syncthreads();
        if (tid < 128) {
            short8 av;
            av[0] = (short)f2bf(f0.x); av[1] = (short)f2bf(f0.y);
            av[2] = (short)f2bf(f0.z); av[3] = (short)f2bf(f0.w);
            av[4] = (short)f2bf(f1.x); av[5] = (short)f2bf(f1.y);
            av[6] = (short)f2bf(f1.z); av[7] = (short)f2bf(f1.w);
            *(short8*)&As[tid >> 2][(tid & 3) * 8] = av;
        }
#pragma unroll
        for (int i = 0; i < 3; ++i) {
            int idx = i * 256 + tid;
            *(short8*)&Bs[idx >> 2][(idx & 3) * 8] = w[i];
        }
        __syncthreads();

        short8 afr[2], bfr[3];
#pragma unroll
        for (int mf = 0; mf < 2; ++mf)
            afr[mf] = *(const short8*)&As[mf * 16 + lr][lk];
#pragma unroll
        for (int nf = 0; nf < 3; ++nf)
            bfr[nf] = *(const short8*)&Bs[wave * 48 + nf * 16 + lr][lk];
#pragma unroll
        for (int mf = 0; mf < 2; ++mf)
#pragma unroll
            for (int nf = 0; nf < 3; ++nf)
                acc[mf][nf] = __builtin_amdgcn_mfma_f32_16x16x32_bf16(
                    afr[mf], bfr[nf], acc[mf][nf], 0, 0, 0);
    }

#pragma unroll
    for (int nf = 0; nf < 3; ++nf) {
        int col = wave * 48 + nf * 16 + lr;
        float bias = (col < 128) ? b_off[col] : b_attn[col - 128];
#pragma unroll
        for (int mf = 0; mf < 2; ++mf) {
#pragma unroll
            for (int r = 0; r < 4; ++r) {
                int m = bm + mf * 16 + (lane >> 4) * 4 + r;
                logits[(size_t)m * 192 + col] = acc[mf][nf][r] + bias;
            }
        }
    }
}

// ---------------------------------------------------------------------------
// Kernel 3: sampling. One block per query (4000 blocks). Fuses softmax.
// Thread (h=tid>>5, d=tid&31) gathers 8 samples x 4 corners, writes mid bf16.
// ---------------------------------------------------------------------------
__global__ __launch_bounds__(256) void sample_kernel(
    const float* __restrict__ logits,  // [4000][192]
    const float* __restrict__ refp,    // [B,NQ,L,2]
    const unsigned short* __restrict__ v,  // [B,H,NV,D] bf16
    unsigned short* __restrict__ mid)      // [4000][256] bf16
{
    __shared__ float offl[128];
    __shared__ float attnl[64];
    __shared__ float refl[8];

    const int q = blockIdx.x;   // b*NQQ + nq
    const int b = q / NQQ;
    const int tid = threadIdx.x;

    if (tid < 192) {
        float t = logits[(size_t)q * 192 + tid];
        if (tid < 128) offl[tid] = t;
        else attnl[tid - 128] = t;
    } else if (tid < 200) {
        refl[tid - 192] = refp[(size_t)q * 8 + (tid - 192)];
    }
    __syncthreads();

    if (tid < 8) {  // softmax over 8 per head, one thread per head
        float m = -1e30f;
#pragma unroll
        for (int j = 0; j < 8; ++j) m = fmaxf(m, attnl[tid * 8 + j]);
        float s = 0.f, e[8];
#pragma unroll
        for (int j = 0; j < 8; ++j) {
            e[j] = __expf(attnl[tid * 8 + j] - m);
            s += e[j];
        }
        float inv = 1.f / s;
#pragma unroll
        for (int j = 0; j < 8; ++j) attnl[tid * 8 + j] = e[j] * inv;
    }
    __syncthreads();

    const int h = tid >> 5, d = tid & 31;
    const unsigned short* vh = v + (size_t)(b * HH + h) * NVV * DD;
    const int starts[4] = {0, 16384, 20480, 21504};
    const float szs[4] = {128.f, 64.f, 32.f, 16.f};

    float acc = 0.f;
#pragma unroll
    for (int l = 0; l < LL; ++l) {
        const float S = szs[l];
        const int Wl = (int)S;
        const float refx = refl[l * 2 + 0];
        const float refy = refl[l * 2 + 1];
        const unsigned short* vl = vh + (size_t)starts[l] * DD;
#pragma unroll
        for (int p = 0; p < PP; ++p) {
            const int oi = h * 16 + l * 4 + p * 2;
            float lx = refx + offl[oi + 0] / S;
            float ly = refy + offl[oi + 1] / S;
            float x = lx * S - 0.5f;
            float y = ly * S - 0.5f;
            float x0f = floorf(x), y0f = floorf(y);
            float fx = x - x0f, fy = y - y0f;
            int x0 = (int)x0f, y0 = (int)y0f;
            float a = attnl[h * 8 + l * 2 + p];
            float sacc = 0.f;
#pragma unroll
            for (int dy = 0; dy < 2; ++dy) {
#pragma unroll
                for (int dx = 0; dx < 2; ++dx) {
                    int xi = x0 + dx, yi = y0 + dy;
                    float w = (dx ? fx : 1.f - fx) * (dy ? fy : 1.f - fy);
                    bool valid = (xi >= 0) && (xi < Wl) && (yi >= 0) && (yi < Wl);
                    int xc = min(max(xi, 0), Wl - 1);
                    int yc = min(max(yi, 0), Wl - 1);
                    float g = bf2f(vl[(size_t)(yc * Wl + xc) * DD + d]);
                    sacc += g * (valid ? w : 0.f);
                }
            }
            acc += a * sacc;
        }
    }
    mid[(size_t)q * CC + h * 32 + d] = f2bf(acc);
}

// ---------------------------------------------------------------------------
// Kernel 4: out[4000,256] = mid_bf16 @ W_out_bf16 + b_out. MFMA, BM=32.
// Grid 125 blocks. Wave w owns cols [64w, 64w+64), 2 row-frags x 4 col-frags.
// ---------------------------------------------------------------------------
__global__ __launch_bounds__(256) void out_mfma(
    const unsigned short* __restrict__ mid, const unsigned short* __restrict__ WoT,
    const float* __restrict__ b_out, float* __restrict__ out)
{
    __shared__ unsigned short As[32][40];
    __shared__ unsigned short Bs[256][40];
    const int tid = threadIdx.x;
    const int lane = tid & 63;
    const int wave = tid >> 6;
    const int bm = blockIdx.x * 32;
    f32x4 acc[2][4] = {};
    const int lr = lane & 15;
    const int lk = (lane >> 4) * 8;

    for (int k0 = 0; k0 < CC; k0 += 32) {
        short8 a0 = {};
        if (tid < 128)
            a0 = *(const short8*)&mid[(size_t)(bm + (tid >> 2)) * CC + k0 + (tid & 3) * 8];
        const unsigned short* bsrc = &WoT[(size_t)tid * CC + k0];
        short8 w0 = *(const short8*)(bsrc);
        short8 w1 = *(const short8*)(bsrc + 8);
        short8 w2 = *(const short8*)(bsrc + 16);
        short8 w3 = *(const short8*)(bsrc + 24);

        __syncthreads();
        if (tid < 128) *(short8*)&As[tid >> 2][(tid & 3) * 8] = a0;
        *(short8*)&Bs[tid][0]  = w0;
        *(short8*)&Bs[tid][8]  = w1;
        *(short8*)&Bs[tid][16] = w2;
        *(short8*)&Bs[tid][24] = w3;
        __syncthreads();

        short8 afr[2], bfr[4];
#pragma unroll
        for (int mf = 0; mf < 2; ++mf)
            afr[mf] = *(const short8*)&As[mf * 16 + lr][lk];
#pragma unroll
        for (int nf = 0; nf < 4; ++nf)
            bfr[nf] = *(const short8*)&Bs[wave * 64 + nf * 16 + lr][lk];
#pragma unroll
        for (int mf = 0; mf < 2; ++mf)
#pragma unroll
            for (int nf = 0; nf < 4; ++nf)
                acc[mf][nf] = __builtin_amdgcn_mfma_f32_16x16x32_bf16(
                    afr[mf], bfr[nf], acc[mf][nf], 0, 0, 0);
    }

#pragma unroll
    for (int nf = 0; nf < 4; ++nf) {
        int col = wave * 64 + nf * 16 + lr;
        float bias = b_out[col];
#pragma unroll
        for (int mf = 0; mf < 2; ++mf) {
#pragma unroll
            for (int r = 0; r < 4; ++r) {
                int m = bm + mf * 16 + (lane >> 4) * 4 + r;
                out[(size_t)m * CC + col] = acc[mf][nf][r] + bias;
            }
        }
    }
}

extern "C" void kernel_launch(void* const* d_in, const int* in_sizes, int n_in,
                              void* d_out, int out_size, void* d_ws, size_t ws_size,
                              hipStream_t stream) {
    const float* query  = (const float*)d_in[0];
    const float* value  = (const float*)d_in[1];
    const float* refp   = (const float*)d_in[2];
    const float* W_off  = (const float*)d_in[3];
    const float* b_off  = (const float*)d_in[4];
    const float* W_attn = (const float*)d_in[5];
    const float* b_attn = (const float*)d_in[6];
    const float* W_val  = (const float*)d_in[7];
    const float* b_val  = (const float*)d_in[8];
    const float* W_out  = (const float*)d_in[9];
    const float* b_out  = (const float*)d_in[10];
    float* out = (float*)d_out;

    char* ws = (char*)d_ws;
    unsigned short* WT_val = (unsigned short*)(ws);                    // 128 KB
    unsigned short* v_ws   = (unsigned short*)(ws + 131072);           // 44.56 MB
    unsigned short* W1T    = (unsigned short*)(ws + 44695552);         // 96 KB
    unsigned short* WoT    = (unsigned short*)(ws + 44793856);         // 128 KB
    float*          logits = (float*)(ws + 44924928);                  // 3 MB
    unsigned short* mid    = (unsigned short*)(ws + 47996928);         // 2 MB

    prep_kernel<<<704, 256, 0, stream>>>(W_val, W_off, W_attn, W_out,
                                         WT_val, W1T, WoT);
    valproj_mfma<<<(BB * NVV) / 64, 256, 0, stream>>>(value, WT_val, b_val, v_ws);
    logits_mfma<<<NQT / 32, 256, 0, stream>>>(query, W1T, b_off, b_attn, logits);
    sample_kernel<<<NQT, 256, 0, stream>>>(logits, refp, v_ws, mid);
    out_mfma<<<NQT / 32, 256, 0, stream>>>(mid, WoT, b_out, out);
}

// Round 4
// 73.306 us; speedup vs baseline: 3.2904x; 1.0612x over previous
//
#include <hip/hip_runtime.h>

#define HH 8
#define LL 4
#define PP 2
#define DD 32
#define CC 256
#define NVV 21760
#define NQQ 1000
#define BB 4
#define NQT (BB * NQQ)   // 4000 total queries

typedef __attribute__((ext_vector_type(8))) short short8;
typedef __attribute__((ext_vector_type(4))) short shortv4;
typedef __attribute__((ext_vector_type(4))) float f32x4;

__device__ __forceinline__ unsigned short f2bf(float f) {
    unsigned u = __float_as_uint(f);
    u += 0x7FFF + ((u >> 16) & 1);  // round-to-nearest-even
    return (unsigned short)(u >> 16);
}
__device__ __forceinline__ float bf2f(unsigned short h) {
    return __uint_as_float(((unsigned)h) << 16);
}

__device__ __forceinline__ void gload_lds16(const void* g, void* l) {
    __builtin_amdgcn_global_load_lds(
        (const __attribute__((address_space(1))) unsigned int*)g,
        (__attribute__((address_space(3))) unsigned int*)l, 16, 0, 0);
}

// ---------------------------------------------------------------------------
// Kernel 0: weight prep. Block c (=k row, 0..255), thread n. Coalesced reads.
//  Wslc[s][n][kin] = bf16(W_val[k=s*32+kin][n])   (k-sliced for gll staging)
//  W1T[n][c] = bf16([W_off|W_attn][c][n]),  WoT[n][c] = bf16(W_out[c][n])
// ---------------------------------------------------------------------------
__global__ __launch_bounds__(256) void prep_kernel(
    const float* __restrict__ Wv, const float* __restrict__ Woff,
    const float* __restrict__ Wattn, const float* __restrict__ Wout,
    unsigned short* __restrict__ Wslc, unsigned short* __restrict__ W1T,
    unsigned short* __restrict__ WoT)
{
    const int c = blockIdx.x;   // k index 0..255
    const int n = threadIdx.x;  // output col 0..255
    Wslc[(c >> 5) * 8192 + n * 32 + (c & 31)] = f2bf(Wv[c * CC + n]);
    if (n < 192) {
        float x = (n < 128) ? Woff[c * 128 + n] : Wattn[c * 64 + (n - 128)];
        W1T[n * CC + c] = f2bf(x);
    }
    WoT[n * CC + c] = f2bf(Wout[c * CC + n]);
}

// ---------------------------------------------------------------------------
// Kernel 1: v[b,h,n,d] (bf16) = value @ W_val + b_val.
// 512 threads (8 waves, 4M x 2N). BM=64, BN=256, BK=32.
// B: double-buffered linear LDS via global_load_lds (async, no VALU).
// A: direct global->VGPR fragment loads (no LDS), prefetched 1 iter ahead.
// One barrier per K-iter.
// ---------------------------------------------------------------------------
__global__ __launch_bounds__(512) void valproj_mfma(
    const float* __restrict__ value, const unsigned short* __restrict__ Wslc,
    const float* __restrict__ bv, unsigned short* __restrict__ v_out)
{
    __shared__ __align__(16) unsigned short Bst[2][8192];  // 2 x 16KB, [n][32]

    const int tid = threadIdx.x;
    const int w = tid >> 6;      // wave 0..7
    const int lane = tid & 63;
    const int wm = w >> 1;       // 0..3: 16-row M group
    const int wn = w & 1;        // 0..1: 128-col N half
    const int lr = lane & 15;
    const int q = lane >> 4;     // k-chunk 0..3
    const int bm = blockIdx.x * 64;
    const int b = bm / NVV;      // NVV % 64 == 0

    const float* arow = value + (size_t)(bm + wm * 16 + lr) * CC;

    f32x4 acc[8] = {};
    float4 a0, a1;

    // stage slice s into buffer c: 8 waves x 2 x 1KB chunks, linear copy
#define STAGE(s, c)                                                         \
    {                                                                       \
        _Pragma("unroll") for (int i = 0; i < 2; ++i) {                     \
            int chunk = (w * 2 + i) * 1024;                                 \
            gload_lds16((const char*)Wslc + (size_t)(s) * 16384 + chunk +   \
                            lane * 16,                                      \
                        (char*)&Bst[c][0] + chunk);                         \
        }                                                                   \
    }
#define LOADA(s)                                                            \
    {                                                                       \
        const float* p = arow + (s) * 32 + q * 8;                           \
        a0 = *(const float4*)p;                                             \
        a1 = *(const float4*)(p + 4);                                       \
    }

    STAGE(0, 0);
    LOADA(0);
    __syncthreads();  // drains vmcnt -> staging + A complete

#pragma unroll
    for (int s = 0; s < 8; ++s) {
        const int cur = s & 1;
        if (s < 7) STAGE(s + 1, cur ^ 1);
        short8 af;
        af[0] = (short)f2bf(a0.x); af[1] = (short)f2bf(a0.y);
        af[2] = (short)f2bf(a0.z); af[3] = (short)f2bf(a0.w);
        af[4] = (short)f2bf(a1.x); af[5] = (short)f2bf(a1.y);
        af[6] = (short)f2bf(a1.z); af[7] = (short)f2bf(a1.w);
        if (s < 7) LOADA(s + 1);
#pragma unroll
        for (int nf = 0; nf < 8; ++nf) {
            short8 bf =
                *(const short8*)&Bst[cur][(wn * 128 + nf * 16 + lr) * 32 + q * 8];
            acc[nf] = __builtin_amdgcn_mfma_f32_16x16x32_bf16(af, bf, acc[nf],
                                                              0, 0, 0);
        }
        __syncthreads();  // drains vmcnt(0): next buffer + next A ready
    }
#undef STAGE
#undef LOADA

#pragma unroll
    for (int nf = 0; nf < 8; ++nf) {
        int col = wn * 128 + nf * 16 + lr;
        int h = col >> 5, d = col & 31;
        float bias = bv[col];
        int n0 = bm - b * NVV + wm * 16 + q * 4;
        size_t obase = (size_t)((b * HH + h) * NVV + n0) * DD + d;
#pragma unroll
        for (int r = 0; r < 4; ++r)
            v_out[obase + (size_t)r * DD] = f2bf(acc[nf][r] + bias);
    }
}

// ---------------------------------------------------------------------------
// Kernel 2: logits[4000,192] = query @ [W_off|W_attn] + bias.
// BM=32, BK=64 (4 iters), 4 waves x 48 cols. Padded LDS rows (72).
// ---------------------------------------------------------------------------
__global__ __launch_bounds__(256) void logits_mfma(
    const float* __restrict__ query, const unsigned short* __restrict__ W1T,
    const float* __restrict__ b_off, const float* __restrict__ b_attn,
    float* __restrict__ logits)
{
    __shared__ unsigned short As[32][72];
    __shared__ unsigned short Bs[192][72];
    const int tid = threadIdx.x;
    const int lane = tid & 63;
    const int wave = tid >> 6;
    const int bm = blockIdx.x * 32;  // 125 blocks * 32 = 4000
    const int lr = lane & 15;
    const int q = lane >> 4;
    f32x4 acc[2][3] = {};

    for (int k0 = 0; k0 < CC; k0 += 64) {
        float4 a[2];
        short8 wv[6];
#pragma unroll
        for (int i = 0; i < 2; ++i) {
            int u = tid + 256 * i;  // 512 float4 units: row=u>>4, col4=(u&15)*4
            a[i] = *(const float4*)&query[(size_t)(bm + (u >> 4)) * CC + k0 +
                                          (u & 15) * 4];
        }
#pragma unroll
        for (int i = 0; i < 6; ++i) {
            int u = tid + 256 * i;  // 1536 16B units: n=u>>3, j=u&7
            wv[i] = *(const short8*)&W1T[(size_t)(u >> 3) * CC + k0 + (u & 7) * 8];
        }
        __syncthreads();
#pragma unroll
        for (int i = 0; i < 2; ++i) {
            int u = tid + 256 * i;
            shortv4 p;
            p[0] = (short)f2bf(a[i].x); p[1] = (short)f2bf(a[i].y);
            p[2] = (short)f2bf(a[i].z); p[3] = (short)f2bf(a[i].w);
            *(shortv4*)&As[u >> 4][(u & 15) * 4] = p;
        }
#pragma unroll
        for (int i = 0; i < 6; ++i) {
            int u = tid + 256 * i;
            *(short8*)&Bs[u >> 3][(u & 7) * 8] = wv[i];
        }
        __syncthreads();

#pragma unroll
        for (int kk = 0; kk < 2; ++kk) {
            short8 afr[2], bfr[3];
#pragma unroll
            for (int mf = 0; mf < 2; ++mf)
                afr[mf] = *(const short8*)&As[mf * 16 + lr][kk * 32 + q * 8];
#pragma unroll
            for (int nf = 0; nf < 3; ++nf)
                bfr[nf] =
                    *(const short8*)&Bs[wave * 48 + nf * 16 + lr][kk * 32 + q * 8];
#pragma unroll
            for (int mf = 0; mf < 2; ++mf)
#pragma unroll
                for (int nf = 0; nf < 3; ++nf)
                    acc[mf][nf] = __builtin_amdgcn_mfma_f32_16x16x32_bf16(
                        afr[mf], bfr[nf], acc[mf][nf], 0, 0, 0);
        }
        __syncthreads();
    }

#pragma unroll
    for (int nf = 0; nf < 3; ++nf) {
        int col = wave * 48 + nf * 16 + lr;
        float bias = (col < 128) ? b_off[col] : b_attn[col - 128];
#pragma unroll
        for (int mf = 0; mf < 2; ++mf)
#pragma unroll
            for (int r = 0; r < 4; ++r) {
                int m = bm + mf * 16 + q * 4 + r;
                logits[(size_t)m * 192 + col] = acc[mf][nf][r] + bias;
            }
    }
}

// ---------------------------------------------------------------------------
// Kernel 3: sampling. One block per query (4000 blocks). Fuses softmax.
// Thread (h=tid>>5, d=tid&31) gathers 8 samples x 4 corners, writes mid bf16.
// ---------------------------------------------------------------------------
__global__ __launch_bounds__(256) void sample_kernel(
    const float* __restrict__ logits,  // [4000][192]
    const float* __restrict__ refp,    // [B,NQ,L,2]
    const unsigned short* __restrict__ v,  // [B,H,NV,D] bf16
    unsigned short* __restrict__ mid)      // [4000][256] bf16
{
    __shared__ float offl[128];
    __shared__ float attnl[64];
    __shared__ float refl[8];

    const int qy = blockIdx.x;  // b*NQQ + nq
    const int b = qy / NQQ;
    const int tid = threadIdx.x;

    if (tid < 192) {
        float t = logits[(size_t)qy * 192 + tid];
        if (tid < 128) offl[tid] = t;
        else attnl[tid - 128] = t;
    } else if (tid < 200) {
        refl[tid - 192] = refp[(size_t)qy * 8 + (tid - 192)];
    }
    __syncthreads();

    if (tid < 8) {
        float m = -1e30f;
#pragma unroll
        for (int j = 0; j < 8; ++j) m = fmaxf(m, attnl[tid * 8 + j]);
        float s = 0.f, e[8];
#pragma unroll
        for (int j = 0; j < 8; ++j) {
            e[j] = __expf(attnl[tid * 8 + j] - m);
            s += e[j];
        }
        float inv = 1.f / s;
#pragma unroll
        for (int j = 0; j < 8; ++j) attnl[tid * 8 + j] = e[j] * inv;
    }
    __syncthreads();

    const int h = tid >> 5, d = tid & 31;
    const unsigned short* vh = v + (size_t)(b * HH + h) * NVV * DD;
    const int starts[4] = {0, 16384, 20480, 21504};
    const float szs[4] = {128.f, 64.f, 32.f, 16.f};

    float acc = 0.f;
#pragma unroll
    for (int l = 0; l < LL; ++l) {
        const float S = szs[l];
        const int Wl = (int)S;
        const float refx = refl[l * 2 + 0];
        const float refy = refl[l * 2 + 1];
        const unsigned short* vl = vh + (size_t)starts[l] * DD;
#pragma unroll
        for (int p = 0; p < PP; ++p) {
            const int oi = h * 16 + l * 4 + p * 2;
            float lx = refx + offl[oi + 0] / S;
            float ly = refy + offl[oi + 1] / S;
            float x = lx * S - 0.5f;
            float y = ly * S - 0.5f;
            float x0f = floorf(x), y0f = floorf(y);
            float fx = x - x0f, fy = y - y0f;
            int x0 = (int)x0f, y0 = (int)y0f;
            float a = attnl[h * 8 + l * 2 + p];
            float sacc = 0.f;
#pragma unroll
            for (int dy = 0; dy < 2; ++dy) {
#pragma unroll
                for (int dx = 0; dx < 2; ++dx) {
                    int xi = x0 + dx, yi = y0 + dy;
                    float wgt = (dx ? fx : 1.f - fx) * (dy ? fy : 1.f - fy);
                    bool valid = (xi >= 0) && (xi < Wl) && (yi >= 0) && (yi < Wl);
                    int xc = min(max(xi, 0), Wl - 1);
                    int yc = min(max(yi, 0), Wl - 1);
                    float g = bf2f(vl[(size_t)(yc * Wl + xc) * DD + d]);
                    sacc += g * (valid ? wgt : 0.f);
                }
            }
            acc += a * sacc;
        }
    }
    mid[(size_t)qy * CC + h * 32 + d] = f2bf(acc);
}

// ---------------------------------------------------------------------------
// Kernel 4: out[4000,256] = mid_bf16 @ W_out_bf16 + b_out.
// BM=32, BK=64 (4 iters), 4 waves x 64 cols. Padded LDS rows (72).
// ---------------------------------------------------------------------------
__global__ __launch_bounds__(256) void out_mfma(
    const unsigned short* __restrict__ mid,
    const unsigned short* __restrict__ WoT, const float* __restrict__ b_out,
    float* __restrict__ out)
{
    __shared__ unsigned short As[32][72];
    __shared__ unsigned short Bs[256][72];
    const int tid = threadIdx.x;
    const int lane = tid & 63;
    const int wave = tid >> 6;
    const int bm = blockIdx.x * 32;
    const int lr = lane & 15;
    const int q = lane >> 4;
    f32x4 acc[2][4] = {};

    for (int k0 = 0; k0 < CC; k0 += 64) {
        short8 a0 = *(const short8*)&mid[(size_t)(bm + (tid >> 3)) * CC + k0 +
                                         (tid & 7) * 8];
        short8 wv[8];
#pragma unroll
        for (int i = 0; i < 8; ++i) {
            int u = tid + 256 * i;  // 2048 16B units: n=u>>3, j=u&7
            wv[i] = *(const short8*)&WoT[(size_t)(u >> 3) * CC + k0 + (u & 7) * 8];
        }
        __syncthreads();
        *(short8*)&As[tid >> 3][(tid & 7) * 8] = a0;
#pragma unroll
        for (int i = 0; i < 8; ++i) {
            int u = tid + 256 * i;
            *(short8*)&Bs[u >> 3][(u & 7) * 8] = wv[i];
        }
        __syncthreads();

#pragma unroll
        for (int kk = 0; kk < 2; ++kk) {
            short8 afr[2], bfr[4];
#pragma unroll
            for (int mf = 0; mf < 2; ++mf)
                afr[mf] = *(const short8*)&As[mf * 16 + lr][kk * 32 + q * 8];
#pragma unroll
            for (int nf = 0; nf < 4; ++nf)
                bfr[nf] =
                    *(const short8*)&Bs[wave * 64 + nf * 16 + lr][kk * 32 + q * 8];
#pragma unroll
            for (int mf = 0; mf < 2; ++mf)
#pragma unroll
                for (int nf = 0; nf < 4; ++nf)
                    acc[mf][nf] = __builtin_amdgcn_mfma_f32_16x16x32_bf16(
                        afr[mf], bfr[nf], acc[mf][nf], 0, 0, 0);
        }
        __syncthreads();
    }

#pragma unroll
    for (int nf = 0; nf < 4; ++nf) {
        int col = wave * 64 + nf * 16 + lr;
        float bias = b_out[col];
#pragma unroll
        for (int mf = 0; mf < 2; ++mf)
#pragma unroll
            for (int r = 0; r < 4; ++r) {
                int m = bm + mf * 16 + q * 4 + r;
                out[(size_t)m * CC + col] = acc[mf][nf][r] + bias;
            }
    }
}

extern "C" void kernel_launch(void* const* d_in, const int* in_sizes, int n_in,
                              void* d_out, int out_size, void* d_ws, size_t ws_size,
                              hipStream_t stream) {
    const float* query  = (const float*)d_in[0];
    const float* value  = (const float*)d_in[1];
    const float* refp   = (const float*)d_in[2];
    const float* W_off  = (const float*)d_in[3];
    const float* b_off  = (const float*)d_in[4];
    const float* W_attn = (const float*)d_in[5];
    const float* b_attn = (const float*)d_in[6];
    const float* W_val  = (const float*)d_in[7];
    const float* b_val  = (const float*)d_in[8];
    const float* W_out  = (const float*)d_in[9];
    const float* b_out  = (const float*)d_in[10];
    float* out = (float*)d_out;

    char* ws = (char*)d_ws;
    unsigned short* Wslc   = (unsigned short*)(ws);                  // 128 KB
    unsigned short* v_ws   = (unsigned short*)(ws + 131072);         // 44.56 MB
    unsigned short* W1T    = (unsigned short*)(ws + 44695552);       // 96 KB
    unsigned short* WoT    = (unsigned short*)(ws + 44793856);       // 128 KB
    float*          logits = (float*)(ws + 44924928);                // 3 MB
    unsigned short* mid    = (unsigned short*)(ws + 47996928);       // 2 MB

    prep_kernel<<<CC, 256, 0, stream>>>(W_val, W_off, W_attn, W_out,
                                        Wslc, W1T, WoT);
    valproj_mfma<<<(BB * NVV) / 64, 512, 0, stream>>>(value, Wslc, b_val, v_ws);
    logits_mfma<<<NQT / 32, 256, 0, stream>>>(query, W1T, b_off, b_attn, logits);
    sample_kernel<<<NQT, 256, 0, stream>>>(logits, refp, v_ws, mid);
    out_mfma<<<NQT / 32, 256, 0, stream>>>(mid, WoT, b_out, out);
}

// Round 5
// 68.148 us; speedup vs baseline: 3.5395x; 1.0757x over previous
//
#include <hip/hip_runtime.h>

#define HH 8
#define LL 4
#define PP 2
#define DD 32
#define CC 256
#define NVV 21760
#define NQQ 1000
#define BB 4
#define NQT (BB * NQQ)   // 4000 total queries

typedef __attribute__((ext_vector_type(8))) short short8;
typedef __attribute__((ext_vector_type(4))) short shortv4;
typedef __attribute__((ext_vector_type(4))) float f32x4;

__device__ __forceinline__ unsigned short f2bf(float f) {
    unsigned u = __float_as_uint(f);
    u += 0x7FFF + ((u >> 16) & 1);  // round-to-nearest-even
    return (unsigned short)(u >> 16);
}
__device__ __forceinline__ float bf2f(unsigned short h) {
    return __uint_as_float(((unsigned)h) << 16);
}

__device__ __forceinline__ void gload_lds16(const void* g, void* l) {
    __builtin_amdgcn_global_load_lds(
        (const __attribute__((address_space(1))) unsigned int*)g,
        (__attribute__((address_space(3))) unsigned int*)l, 16, 0, 0);
}

// ---------------------------------------------------------------------------
// Kernel 0: weight prep. Block c (=k row, 0..255), thread n. Coalesced reads.
//  Wslc[s][n][kin] = bf16(W_val[k=s*32+kin][n])   (k-sliced for gll staging)
//  W1T[n][c] = bf16([W_off|W_attn][c][n]),  WoT[n][c] = bf16(W_out[c][n])
// ---------------------------------------------------------------------------
__global__ __launch_bounds__(256) void prep_kernel(
    const float* __restrict__ Wv, const float* __restrict__ Woff,
    const float* __restrict__ Wattn, const float* __restrict__ Wout,
    unsigned short* __restrict__ Wslc, unsigned short* __restrict__ W1T,
    unsigned short* __restrict__ WoT)
{
    const int c = blockIdx.x;   // k index 0..255
    const int n = threadIdx.x;  // output col 0..255
    Wslc[(c >> 5) * 8192 + n * 32 + (c & 31)] = f2bf(Wv[c * CC + n]);
    if (n < 192) {
        float x = (n < 128) ? Woff[c * 128 + n] : Wattn[c * 64 + (n - 128)];
        W1T[n * CC + c] = f2bf(x);
    }
    WoT[n * CC + c] = f2bf(Wout[c * CC + n]);
}

// ---------------------------------------------------------------------------
// Kernel 1: v[b,h,n,d] (bf16) = value @ W_val + b_val.
// B (128 KB) loaded into LDS ONCE per block; main loop has NO barriers.
// 512 threads (8 waves), BM=128: wave w owns rows w*16..w*16+15, all 256 cols.
// All 16 A-loads issued up front after the single barrier; compiler vmcnt
// waits stream A from HBM under compute. acc=64 VGPR, A-buf=64 VGPR.
// ---------------------------------------------------------------------------
__global__ __launch_bounds__(512) void valproj_mfma(
    const float* __restrict__ value, const unsigned short* __restrict__ Wslc,
    const float* __restrict__ bv, unsigned short* __restrict__ v_out)
{
    __shared__ __align__(16) unsigned short Bs[8][256][32];  // 128 KB

    const int tid = threadIdx.x;
    const int w = tid >> 6;      // wave 0..7 -> 16-row M strip
    const int lane = tid & 63;
    const int lr = lane & 15;
    const int q = lane >> 4;     // k-chunk / row-quad
    const int bm = blockIdx.x * 128;   // 680 blocks; 21760 % 128 == 0
    const int b = bm / NVV;

    // one-time B stage: 128 KB linear global->LDS, async, single barrier
#pragma unroll
    for (int i = 0; i < 16; ++i) {
        size_t off = (size_t)i * 8192 + (size_t)tid * 16;  // bytes
        gload_lds16((const char*)Wslc + off, (char*)&Bs[0][0][0] + off);
    }
    __syncthreads();

    // issue ALL A loads (32 KB/wave) now; waits are per-slice vmcnt
    const float* arow = value + (size_t)(bm + w * 16 + lr) * CC;
    float4 a0[8], a1[8];
#pragma unroll
    for (int s = 0; s < 8; ++s) {
        const float* p = arow + s * 32 + q * 8;
        a0[s] = *(const float4*)p;
        a1[s] = *(const float4*)(p + 4);
    }

    f32x4 acc[16] = {};
#pragma unroll
    for (int s = 0; s < 8; ++s) {
        short8 af;
        af[0] = (short)f2bf(a0[s].x); af[1] = (short)f2bf(a0[s].y);
        af[2] = (short)f2bf(a0[s].z); af[3] = (short)f2bf(a0[s].w);
        af[4] = (short)f2bf(a1[s].x); af[5] = (short)f2bf(a1[s].y);
        af[6] = (short)f2bf(a1[s].z); af[7] = (short)f2bf(a1[s].w);
#pragma unroll
        for (int nf = 0; nf < 16; ++nf) {
            short8 bf = *(const short8*)&Bs[s][nf * 16 + lr][q * 8];
            acc[nf] = __builtin_amdgcn_mfma_f32_16x16x32_bf16(af, bf, acc[nf],
                                                              0, 0, 0);
        }
    }

#pragma unroll
    for (int nf = 0; nf < 16; ++nf) {
        int col = nf * 16 + lr;
        int h = col >> 5, d = col & 31;
        float bias = bv[col];
        int n0 = bm - b * NVV + w * 16 + q * 4;
        size_t obase = (size_t)((b * HH + h) * NVV + n0) * DD + d;
#pragma unroll
        for (int r = 0; r < 4; ++r)
            v_out[obase + (size_t)r * DD] = f2bf(acc[nf][r] + bias);
    }
}

// ---------------------------------------------------------------------------
// Kernel 2: logits[4000,192] = query @ [W_off|W_attn] + bias.
// BM=32, BK=64 (4 iters), 4 waves x 48 cols. Padded LDS rows (72).
// ---------------------------------------------------------------------------
__global__ __launch_bounds__(256) void logits_mfma(
    const float* __restrict__ query, const unsigned short* __restrict__ W1T,
    const float* __restrict__ b_off, const float* __restrict__ b_attn,
    float* __restrict__ logits)
{
    __shared__ unsigned short As[32][72];
    __shared__ unsigned short Bs[192][72];
    const int tid = threadIdx.x;
    const int lane = tid & 63;
    const int wave = tid >> 6;
    const int bm = blockIdx.x * 32;  // 125 blocks * 32 = 4000
    const int lr = lane & 15;
    const int q = lane >> 4;
    f32x4 acc[2][3] = {};

    for (int k0 = 0; k0 < CC; k0 += 64) {
        float4 a[2];
        short8 wv[6];
#pragma unroll
        for (int i = 0; i < 2; ++i) {
            int u = tid + 256 * i;  // 512 float4 units: row=u>>4, col4=(u&15)*4
            a[i] = *(const float4*)&query[(size_t)(bm + (u >> 4)) * CC + k0 +
                                          (u & 15) * 4];
        }
#pragma unroll
        for (int i = 0; i < 6; ++i) {
            int u = tid + 256 * i;  // 1536 16B units: n=u>>3, j=u&7
            wv[i] = *(const short8*)&W1T[(size_t)(u >> 3) * CC + k0 + (u & 7) * 8];
        }
        __syncthreads();
#pragma unroll
        for (int i = 0; i < 2; ++i) {
            int u = tid + 256 * i;
            shortv4 p;
            p[0] = (short)f2bf(a[i].x); p[1] = (short)f2bf(a[i].y);
            p[2] = (short)f2bf(a[i].z); p[3] = (short)f2bf(a[i].w);
            *(shortv4*)&As[u >> 4][(u & 15) * 4] = p;
        }
#pragma unroll
        for (int i = 0; i < 6; ++i) {
            int u = tid + 256 * i;
            *(short8*)&Bs[u >> 3][(u & 7) * 8] = wv[i];
        }
        __syncthreads();

#pragma unroll
        for (int kk = 0; kk < 2; ++kk) {
            short8 afr[2], bfr[3];
#pragma unroll
            for (int mf = 0; mf < 2; ++mf)
                afr[mf] = *(const short8*)&As[mf * 16 + lr][kk * 32 + q * 8];
#pragma unroll
            for (int nf = 0; nf < 3; ++nf)
                bfr[nf] =
                    *(const short8*)&Bs[wave * 48 + nf * 16 + lr][kk * 32 + q * 8];
#pragma unroll
            for (int mf = 0; mf < 2; ++mf)
#pragma unroll
                for (int nf = 0; nf < 3; ++nf)
                    acc[mf][nf] = __builtin_amdgcn_mfma_f32_16x16x32_bf16(
                        afr[mf], bfr[nf], acc[mf][nf], 0, 0, 0);
        }
        __syncthreads();
    }

#pragma unroll
    for (int nf = 0; nf < 3; ++nf) {
        int col = wave * 48 + nf * 16 + lr;
        float bias = (col < 128) ? b_off[col] : b_attn[col - 128];
#pragma unroll
        for (int mf = 0; mf < 2; ++mf)
#pragma unroll
            for (int r = 0; r < 4; ++r) {
                int m = bm + mf * 16 + q * 4 + r;
                logits[(size_t)m * 192 + col] = acc[mf][nf][r] + bias;
            }
    }
}

// ---------------------------------------------------------------------------
// Kernel 3: sampling. One block per query (4000 blocks). Fuses softmax.
// Thread (h=tid>>5, d=tid&31) gathers 8 samples x 4 corners, writes mid bf16.
// ---------------------------------------------------------------------------
__global__ __launch_bounds__(256) void sample_kernel(
    const float* __restrict__ logits,  // [4000][192]
    const float* __restrict__ refp,    // [B,NQ,L,2]
    const unsigned short* __restrict__ v,  // [B,H,NV,D] bf16
    unsigned short* __restrict__ mid)      // [4000][256] bf16
{
    __shared__ float offl[128];
    __shared__ float attnl[64];
    __shared__ float refl[8];

    const int qy = blockIdx.x;  // b*NQQ + nq
    const int b = qy / NQQ;
    const int tid = threadIdx.x;

    if (tid < 192) {
        float t = logits[(size_t)qy * 192 + tid];
        if (tid < 128) offl[tid] = t;
        else attnl[tid - 128] = t;
    } else if (tid < 200) {
        refl[tid - 192] = refp[(size_t)qy * 8 + (tid - 192)];
    }
    __syncthreads();

    if (tid < 8) {
        float m = -1e30f;
#pragma unroll
        for (int j = 0; j < 8; ++j) m = fmaxf(m, attnl[tid * 8 + j]);
        float s = 0.f, e[8];
#pragma unroll
        for (int j = 0; j < 8; ++j) {
            e[j] = __expf(attnl[tid * 8 + j] - m);
            s += e[j];
        }
        float inv = 1.f / s;
#pragma unroll
        for (int j = 0; j < 8; ++j) attnl[tid * 8 + j] = e[j] * inv;
    }
    __syncthreads();

    const int h = tid >> 5, d = tid & 31;
    const unsigned short* vh = v + (size_t)(b * HH + h) * NVV * DD;
    const int starts[4] = {0, 16384, 20480, 21504};
    const float szs[4] = {128.f, 64.f, 32.f, 16.f};

    float acc = 0.f;
#pragma unroll
    for (int l = 0; l < LL; ++l) {
        const float S = szs[l];
        const int Wl = (int)S;
        const float refx = refl[l * 2 + 0];
        const float refy = refl[l * 2 + 1];
        const unsigned short* vl = vh + (size_t)starts[l] * DD;
#pragma unroll
        for (int p = 0; p < PP; ++p) {
            const int oi = h * 16 + l * 4 + p * 2;
            float lx = refx + offl[oi + 0] / S;
            float ly = refy + offl[oi + 1] / S;
            float x = lx * S - 0.5f;
            float y = ly * S - 0.5f;
            float x0f = floorf(x), y0f = floorf(y);
            float fx = x - x0f, fy = y - y0f;
            int x0 = (int)x0f, y0 = (int)y0f;
            float a = attnl[h * 8 + l * 2 + p];
            float sacc = 0.f;
#pragma unroll
            for (int dy = 0; dy < 2; ++dy) {
#pragma unroll
                for (int dx = 0; dx < 2; ++dx) {
                    int xi = x0 + dx, yi = y0 + dy;
                    float wgt = (dx ? fx : 1.f - fx) * (dy ? fy : 1.f - fy);
                    bool valid = (xi >= 0) && (xi < Wl) && (yi >= 0) && (yi < Wl);
                    int xc = min(max(xi, 0), Wl - 1);
                    int yc = min(max(yi, 0), Wl - 1);
                    float g = bf2f(vl[(size_t)(yc * Wl + xc) * DD + d]);
                    sacc += g * (valid ? wgt : 0.f);
                }
            }
            acc += a * sacc;
        }
    }
    mid[(size_t)qy * CC + h * 32 + d] = f2bf(acc);
}

// ---------------------------------------------------------------------------
// Kernel 4: out[4000,256] = mid_bf16 @ W_out_bf16 + b_out.
// BM=32, BK=64 (4 iters), 4 waves x 64 cols. Padded LDS rows (72).
// ---------------------------------------------------------------------------
__global__ __launch_bounds__(256) void out_mfma(
    const unsigned short* __restrict__ mid,
    const unsigned short* __restrict__ WoT, const float* __restrict__ b_out,
    float* __restrict__ out)
{
    __shared__ unsigned short As[32][72];
    __shared__ unsigned short Bs[256][72];
    const int tid = threadIdx.x;
    const int lane = tid & 63;
    const int wave = tid >> 6;
    const int bm = blockIdx.x * 32;
    const int lr = lane & 15;
    const int q = lane >> 4;
    f32x4 acc[2][4] = {};

    for (int k0 = 0; k0 < CC; k0 += 64) {
        short8 a0 = *(const short8*)&mid[(size_t)(bm + (tid >> 3)) * CC + k0 +
                                         (tid & 7) * 8];
        short8 wv[8];
#pragma unroll
        for (int i = 0; i < 8; ++i) {
            int u = tid + 256 * i;  // 2048 16B units: n=u>>3, j=u&7
            wv[i] = *(const short8*)&WoT[(size_t)(u >> 3) * CC + k0 + (u & 7) * 8];
        }
        __syncthreads();
        *(short8*)&As[tid >> 3][(tid & 7) * 8] = a0;
#pragma unroll
        for (int i = 0; i < 8; ++i) {
            int u = tid + 256 * i;
            *(short8*)&Bs[u >> 3][(u & 7) * 8] = wv[i];
        }
        __syncthreads();

#pragma unroll
        for (int kk = 0; kk < 2; ++kk) {
            short8 afr[2], bfr[4];
#pragma unroll
            for (int mf = 0; mf < 2; ++mf)
                afr[mf] = *(const short8*)&As[mf * 16 + lr][kk * 32 + q * 8];
#pragma unroll
            for (int nf = 0; nf < 4; ++nf)
                bfr[nf] =
                    *(const short8*)&Bs[wave * 64 + nf * 16 + lr][kk * 32 + q * 8];
#pragma unroll
            for (int mf = 0; mf < 2; ++mf)
#pragma unroll
                for (int nf = 0; nf < 4; ++nf)
                    acc[mf][nf] = __builtin_amdgcn_mfma_f32_16x16x32_bf16(
                        afr[mf], bfr[nf], acc[mf][nf], 0, 0, 0);
        }
        __syncthreads();
    }

#pragma unroll
    for (int nf = 0; nf < 4; ++nf) {
        int col = wave * 64 + nf * 16 + lr;
        float bias = b_out[col];
#pragma unroll
        for (int mf = 0; mf < 2; ++mf)
#pragma unroll
            for (int r = 0; r < 4; ++r) {
                int m = bm + mf * 16 + q * 4 + r;
                out[(size_t)m * CC + col] = acc[mf][nf][r] + bias;
            }
    }
}

extern "C" void kernel_launch(void* const* d_in, const int* in_sizes, int n_in,
                              void* d_out, int out_size, void* d_ws, size_t ws_size,
                              hipStream_t stream) {
    const float* query  = (const float*)d_in[0];
    const float* value  = (const float*)d_in[1];
    const float* refp   = (const float*)d_in[2];
    const float* W_off  = (const float*)d_in[3];
    const float* b_off  = (const float*)d_in[4];
    const float* W_attn = (const float*)d_in[5];
    const float* b_attn = (const float*)d_in[6];
    const float* W_val  = (const float*)d_in[7];
    const float* b_val  = (const float*)d_in[8];
    const float* W_out  = (const float*)d_in[9];
    const float* b_out  = (const float*)d_in[10];
    float* out = (float*)d_out;

    char* ws = (char*)d_ws;
    unsigned short* Wslc   = (unsigned short*)(ws);                  // 128 KB
    unsigned short* v_ws   = (unsigned short*)(ws + 131072);         // 44.56 MB
    unsigned short* W1T    = (unsigned short*)(ws + 44695552);       // 96 KB
    unsigned short* WoT    = (unsigned short*)(ws + 44793856);       // 128 KB
    float*          logits = (float*)(ws + 44924928);                // 3 MB
    unsigned short* mid    = (unsigned short*)(ws + 47996928);       // 2 MB

    prep_kernel<<<CC, 256, 0, stream>>>(W_val, W_off, W_attn, W_out,
                                        Wslc, W1T, WoT);
    valproj_mfma<<<(BB * NVV) / 128, 512, 0, stream>>>(value, Wslc, b_val, v_ws);
    logits_mfma<<<NQT / 32, 256, 0, stream>>>(query, W1T, b_off, b_attn, logits);
    sample_kernel<<<NQT, 256, 0, stream>>>(logits, refp, v_ws, mid);
    out_mfma<<<NQT / 32, 256, 0, stream>>>(mid, WoT, b_out, out);
}